// Round 7
// baseline (930.688 us; speedup 1.0000x reference)
//
#include <hip/hip_runtime.h>

#define DI __device__ __forceinline__

constexpr int BATCH = 256;
constexpr int INF   = 4096;   // in_features
constexpr int NGRP  = 1024;   // INF/4
constexpr int MOUT  = 4096;   // out_features

constexpr int BM = 64, BN = 64;   // block output tile
constexpr int WKS = 8;            // k-slices (one per wave pair)
constexpr int WK  = INF / WKS;    // 512 k per wave
constexpr int NH  = WK / 32;      // 16 half-steps of k=32
constexpr int RS  = 36;           // reduction row stride (f32), 16B-aligned

using bf16x8 = __attribute__((ext_vector_type(8))) short;
using f32x4  = __attribute__((ext_vector_type(4))) float;

// D4 half-codebook, stored as 2x the actual values (int8); actual = v * 0.5
__device__ __constant__ signed char D4_I8[512] = {
     0, 0, 0, 0,  -4, 0, 0, 0,  -2,-2,-2,-2,  -2,-2,-2, 0,  -2,-2,-2, 2,  -2,-2, 0,-2,  -2,-2, 0, 0,  -2,-2, 0, 2,
    -2,-2, 2,-2,  -2,-2, 2, 0,  -2,-2, 2, 2,  -2, 0,-2,-2,  -2, 0,-2, 0,  -2, 0,-2, 2,  -2, 0, 0,-2,  -2, 0, 0, 0,
    -2, 0, 0, 2,  -2, 0, 2,-2,  -2, 0, 2, 0,  -2, 0, 2, 2,  -2, 2,-2,-2,  -2, 2,-2, 0,  -2, 2,-2, 2,  -2, 2, 0,-2,
    -2, 2, 0, 0,  -2, 2, 0, 2,  -2, 2, 2,-2,  -2, 2, 2, 0,  -2, 2, 2, 2,   0,-4, 0, 0,   0,-2,-2,-2,   0,-2,-2, 0,
     0,-2,-2, 2,   0,-2, 0,-2,   0,-2, 0, 0,   0,-2, 0, 2,   0,-2, 2,-2,   0,-2, 2, 0,   0,-2, 2, 2,   0, 0,-4, 0,
     0, 0,-2,-2,   0, 0,-2, 0,   0, 0,-2, 2,   0, 0, 0,-4,   0, 0, 0,-2,
    -3,-1,-3,-1,  -3,-1,-3, 1,  -3,-1,-1,-3,  -3,-1,-1,-1,  -3,-1,-1, 1,  -3,-1,-1, 3,  -3,-1, 1,-3,  -3,-1, 1,-1,
    -3,-1, 1, 1,  -3,-1, 1, 3,  -3,-1, 3,-1,  -3,-1, 3, 1,  -3, 1,-3,-1,  -3, 1,-3, 1,  -3, 1,-1,-3,  -3, 1,-1,-1,
    -3, 1,-1, 1,  -3, 1,-1, 3,  -3, 1, 1,-3,  -3, 1, 1,-1,  -3, 1, 1, 1,  -3, 1, 1, 3,  -3, 1, 3,-1,  -3, 1, 3, 1,
    -3, 3,-1,-1,  -3, 3, 1,-1,  -3, 3, 1, 1,  -1,-3,-3,-1,  -1,-3,-3, 1,  -1,-3,-1,-3,  -1,-3,-1,-1,  -1,-3,-1, 1,
    -1,-3,-1, 3,  -1,-3, 1,-3,  -1,-3, 1,-1,  -1,-3, 1, 1,  -1,-3, 1, 3,  -1,-3, 3,-1,  -1,-3, 3, 1,  -1,-1,-3,-3,
    -1,-1,-3,-1,  -1,-1,-3, 1,  -1,-1,-3, 3,  -1,-1,-1,-3,  -1,-1,-1,-1,  -1,-1,-1, 1,  -1,-1,-1, 3,  -1,-1, 1,-3,
    -1,-1, 1,-1,  -1,-1, 1, 1,  -1,-1, 1, 3,  -1,-1, 3,-3,  -1,-1, 3,-1,  -1,-1, 3, 1,  -1,-1, 3, 3,  -1, 1,-3,-3,
    -1, 1,-3,-1,  -1, 1,-3, 1,  -1, 1,-3, 3,  -1, 1,-1,-3,  -1, 1,-1,-1,  -1, 1,-1, 1,  -1, 1,-1, 3,  -1, 1, 1,-3,
    -1, 1, 1,-1,  -1, 1, 1, 1,  -1, 1, 1, 3,  -1, 1, 3,-3,  -1, 1, 3,-1,  -1, 1, 3, 1,  -1, 1, 3, 3,  -1, 3,-3,-1,
    -1, 3,-3, 1,  -1, 3,-1,-3,  -1, 3,-1,-1,  -1, 3,-1, 1,  -1, 3,-1, 3,  -1, 3, 1,-3,  -1, 3, 1,-1,  -1, 3, 1, 1,
    -1, 3, 1, 3,  -1, 3, 3,-1,  -1, 3, 3, 1
};

DI unsigned short f2bf(float f) {  // f32 -> bf16 bits, round-to-nearest-even
  unsigned int u = __float_as_uint(f);
  u += 0x7fffu + ((u >> 16) & 1u);
  return (unsigned short)(u >> 16);
}

DI float chew8(bf16x8 v, float s) {  // cheap keep-alive fold (2 VALU)
  union { bf16x8 v; f32x4 f; } u; u.v = v;
  return s + u.f[0] + u.f[3];
}

// Build Xa = scaled input in fragment-linear layout Xa[k>>5][m][(k>>3)&3][8]
__global__ __launch_bounds__(256) void prep_kernel(
    const float* __restrict__ inp, const float* __restrict__ sw,
    const float* __restrict__ qs, unsigned short* __restrict__ xa) {
  int i  = blockIdx.x * 256 + threadIdx.x;  // slot id, 131072 total
  int j  = i & 3;                           // k-oct within 32-block
  int m  = (i >> 2) & 255;
  int kb = i >> 10;                         // k >> 5
  const float* ip = inp + (size_t)m * INF + kb * 32 + j * 8;
  float4 f0 = *reinterpret_cast<const float4*>(ip);
  float4 f1 = *reinterpret_cast<const float4*>(ip + 4);
  const float* sp = sw + kb * 32 + j * 8;
  float4 s0 = *reinterpret_cast<const float4*>(sp);
  float4 s1 = *reinterpret_cast<const float4*>(sp + 4);
  int g = kb * 8 + j * 2;
  float q0 = qs[g], q1 = qs[g + 1];
  union { unsigned short u[8]; uint4 v; } o;
  o.u[0] = f2bf(f0.x * s0.x * q0); o.u[1] = f2bf(f0.y * s0.y * q0);
  o.u[2] = f2bf(f0.z * s0.z * q0); o.u[3] = f2bf(f0.w * s0.w * q0);
  o.u[4] = f2bf(f1.x * s1.x * q1); o.u[5] = f2bf(f1.y * s1.y * q1);
  o.u[6] = f2bf(f1.z * s1.z * q1); o.u[7] = f2bf(f1.w * s1.w * q1);
  reinterpret_cast<uint4*>(xa)[i] = o.v;
}

// Repack Qidxs (int32 [MOUT][NGRP]) -> Qp u16 [B4=k>>5][n][j=koct] (4 MB).
__global__ __launch_bounds__(256) void repack_kernel(
    const int* __restrict__ qidx, unsigned short* __restrict__ qp) {
  __shared__ unsigned short lw[16384];     // 32 KB: [B4(128)][n(32)][j(4)]
  const int t  = threadIdx.x;
  const int n0 = blockIdx.x * 32;
  char* lwb = reinterpret_cast<char*>(lw);

  const int b4w   = t >> 1;
  const int cbase = b4w * 256 + ((2 * t) & 3) * 2;
  const int xk    = (b4w & 31) << 3;
  for (int r = 0; r < 32; ++r) {
    int4 v = *reinterpret_cast<const int4*>(
        qidx + (size_t)(n0 + r) * NGRP + t * 4);
    unsigned p01 = (v.x & 255) | ((v.y & 255) << 8) |
                   ((v.z & 255) << 16) | ((unsigned)(v.w & 255) << 24);
    *reinterpret_cast<unsigned*>(lwb + cbase + ((r * 8) ^ xk)) = p01;
  }
  __syncthreads();
  for (int it = 0; it < 16; ++it) {
    int b4 = it * 8 + (t >> 5);
    int n  = t & 31;
    unsigned long long v = *reinterpret_cast<const unsigned long long*>(
        lwb + b4 * 256 + ((n * 8) ^ ((b4 & 31) << 3)));
    *reinterpret_cast<unsigned long long*>(
        reinterpret_cast<char*>(qp) + (size_t)b4 * 32768 +
        (size_t)(n0 + n) * 8) = v;
  }
}

// ================= ABLATION PROBES (write keep-alive sums to scratch) =======
// V0: full pipelined | V1: q+LDS-lookup only | V2: q+A global loads only |
// V3: MFMA only (const frags) | V4: full, unpipelined. Same geometry/LDS as
// the real gemm so occupancy matches.
template <int V, int R>
__global__ __launch_bounds__(1024, 4) void probe_kernel(
    const unsigned short* __restrict__ xa, const unsigned short* __restrict__ qp,
    float* __restrict__ dst) {
  constexpr bool DO_Q  = (V == 0 || V == 1 || V == 2 || V == 4);
  constexpr bool DO_A  = (V == 0 || V == 2 || V == 4);
  constexpr bool DO_DS = (V == 0 || V == 1 || V == 4);
  constexpr bool DO_MF = (V == 0 || V == 3 || V == 4);
  constexpr bool PIPE  = (V != 4);

  __shared__ unsigned long long tbl[256];
  __shared__ float red[8][BM * RS];

  const int tid  = threadIdx.x;
  const int lane = tid & 63;
  const int wave = tid >> 6;
  const int wk   = wave >> 1;
  const int wn   = wave & 1;
  const int l15  = lane & 15, l4 = lane >> 4;

  const int bid = blockIdx.x;
  const int nt  = (bid & 7) * 8 + ((bid >> 3) & 7);
  const int mt  = bid >> 6;
  const int m0 = mt * BM, n0 = nt * BN;

  if (tid < 256) {
    int r = tid & 127, sg = tid >> 7;
    unsigned long long v = 0;
#pragma unroll
    for (int j = 0; j < 4; ++j) {
      float f = (float)D4_I8[r * 4 + j] * 0.5f;
      unsigned int b = __float_as_uint(f) ^ (sg ? 0x80000000u : 0u);
      v |= (unsigned long long)(b >> 16) << (16 * j);
    }
    tbl[tid] = v;
  }
  __syncthreads();

  const unsigned short* aw =
      xa + ((size_t)(wk * 16) * 1024 + (m0 + l15) * 4 + l4) * 8;
  const unsigned short* qw =
      qp + (size_t)(wk * 16) * 16384 + (n0 + wn * 32 + l15) * 4 + l4;

  f32x4          acc[4][2] = {};
  float          sum = 0.f;
  unsigned short qbuf[3][2] = {};
  bf16x8         abuf[2][4];
  bf16x8         bbuf[2][2];

  if constexpr (V == 3) {   // constant fragments from LDS once
    union { unsigned long long u[2]; bf16x8 v; } c;
    c.u[0] = tbl[lane & 255];
    c.u[1] = tbl[255 - (lane & 255)];
#pragma unroll
    for (int mi = 0; mi < 4; ++mi) { abuf[0][mi] = c.v; abuf[1][mi] = c.v; }
#pragma unroll
    for (int ni = 0; ni < 2; ++ni) { bbuf[0][ni] = c.v; bbuf[1][ni] = c.v; }
  }

  auto qload = [&](int s, int t) {
    if (t < NH)
#pragma unroll
      for (int ni = 0; ni < 2; ++ni)
        qbuf[s][ni] = qw[(size_t)t * 16384 + ni * 64];
  };
  auto aload = [&](int s, int t) {
    if (t < NH)
#pragma unroll
      for (int mi = 0; mi < 4; ++mi)
        abuf[s][mi] = *reinterpret_cast<const bf16x8*>(
            aw + (size_t)t * 8192 + mi * 512);
  };
  auto blook = [&](int s, int qs) {
#pragma unroll
    for (int ni = 0; ni < 2; ++ni) {
      unsigned q = qbuf[qs][ni];
      union { unsigned long long u[2]; bf16x8 v; } c;
      c.u[0] = tbl[q & 255];
      c.u[1] = tbl[q >> 8];
      bbuf[s][ni] = c.v;
    }
  };
  auto domfma = [&](int sa, int sb) {
#pragma unroll
    for (int mi = 0; mi < 4; ++mi)
#pragma unroll
      for (int ni = 0; ni < 2; ++ni)
        acc[mi][ni] = __builtin_amdgcn_mfma_f32_16x16x32_bf16(
            abuf[sa][mi], bbuf[sb][ni], acc[mi][ni], 0, 0, 0);
  };

  for (int rep = 0; rep < R; ++rep) {
    if constexpr (PIPE) {
      if constexpr (DO_Q) { qload(0, 0); qload(1, 1); }
      if constexpr (DO_A) aload(0, 0);
      if constexpr (DO_DS) blook(0, 0);
#pragma unroll
      for (int t = 0; t < NH; ++t) {
        if constexpr (DO_Q) qload((t + 2) % 3, t + 2);
        if constexpr (DO_A) aload((t + 1) & 1, t + 1);
        if constexpr (DO_DS) blook((t + 1) & 1, (t + 1) % 3);
        if constexpr (DO_MF) domfma(V == 3 ? 0 : (t & 1), V == 3 ? 0 : (t & 1));
        if constexpr (V == 1) {   // consume what MFMA(t) would consume
          sum = chew8(bbuf[t & 1][0], sum);
          sum = chew8(bbuf[t & 1][1], sum);
        }
        if constexpr (V == 2) {
          sum += (float)qbuf[(t + 1) % 3][0] + (float)qbuf[(t + 1) % 3][1];
#pragma unroll
          for (int mi = 0; mi < 4; ++mi) sum = chew8(abuf[t & 1][mi], sum);
        }
      }
    } else {   // V4: plain order, no pipeline
      for (int t = 0; t < NH; ++t) {
        qload(0, t);
        blook(0, 0);
        aload(0, t);
        domfma(0, 0);
      }
    }
  }

  if constexpr (DO_MF)
#pragma unroll
    for (int mi = 0; mi < 4; ++mi)
#pragma unroll
      for (int ni = 0; ni < 2; ++ni)
#pragma unroll
        for (int r = 0; r < 4; ++r) sum += acc[mi][ni][r];

  // keep red[] allocated (occupancy parity), race-free unique slots
  red[tid >> 7][tid & 127] = sum;
  __syncthreads();
  sum += red[(tid >> 7) ^ 1][tid & 127] * 1e-30f;

  dst[(size_t)bid * 1024 + tid] = sum;
}

// ================= real gemm (round-6, known-passing, unchanged) ===========
__global__ __launch_bounds__(1024, 4) void gemm_kernel(
    const unsigned short* __restrict__ xa, const unsigned short* __restrict__ qp,
    float* __restrict__ out) {
  __shared__ unsigned long long tbl[256];
  __shared__ float red[8][BM * RS];

  const int tid  = threadIdx.x;
  const int lane = tid & 63;
  const int wave = tid >> 6;
  const int wk   = wave >> 1;
  const int wn   = wave & 1;
  const int l15  = lane & 15, l4 = lane >> 4;

  const int bid = blockIdx.x;
  const int nt  = (bid & 7) * 8 + ((bid >> 3) & 7);
  const int mt  = bid >> 6;
  const int m0 = mt * BM, n0 = nt * BN;

  if (tid < 256) {
    int r = tid & 127, sg = tid >> 7;
    unsigned long long v = 0;
#pragma unroll
    for (int j = 0; j < 4; ++j) {
      float f = (float)D4_I8[r * 4 + j] * 0.5f;
      unsigned int b = __float_as_uint(f) ^ (sg ? 0x80000000u : 0u);
      v |= (unsigned long long)(b >> 16) << (16 * j);
    }
    tbl[tid] = v;
  }
  __syncthreads();

  const unsigned short* aw =
      xa + ((size_t)(wk * 16) * 1024 + (m0 + l15) * 4 + l4) * 8;
  const unsigned short* qw =
      qp + (size_t)(wk * 16) * 16384 + (n0 + wn * 32 + l15) * 4 + l4;

  f32x4          acc[4][2] = {};
  unsigned short qbuf[3][2] = {};
  bf16x8         abuf[2][4];
  bf16x8         bbuf[2][2];

  auto qload = [&](int s, int t) {
    if (t < NH)
#pragma unroll
      for (int ni = 0; ni < 2; ++ni)
        qbuf[s][ni] = qw[(size_t)t * 16384 + ni * 64];
  };
  auto aload = [&](int s, int t) {
    if (t < NH)
#pragma unroll
      for (int mi = 0; mi < 4; ++mi)
        abuf[s][mi] = *reinterpret_cast<const bf16x8*>(
            aw + (size_t)t * 8192 + mi * 512);
  };
  auto blook = [&](int s, int qs) {
#pragma unroll
    for (int ni = 0; ni < 2; ++ni) {
      unsigned q = qbuf[qs][ni];
      union { unsigned long long u[2]; bf16x8 v; } c;
      c.u[0] = tbl[q & 255];
      c.u[1] = tbl[q >> 8];
      bbuf[s][ni] = c.v;
    }
  };

  qload(0, 0);
  qload(1, 1);
  aload(0, 0);
  blook(0, 0);

#pragma unroll
  for (int t = 0; t < NH; ++t) {
    qload((t + 2) % 3, t + 2);
    aload((t + 1) & 1, t + 1);
    blook((t + 1) & 1, (t + 1) % 3);
#pragma unroll
    for (int mi = 0; mi < 4; ++mi)
#pragma unroll
      for (int ni = 0; ni < 2; ++ni)
        acc[mi][ni] = __builtin_amdgcn_mfma_f32_16x16x32_bf16(
            abuf[t & 1][mi], bbuf[t & 1][ni], acc[mi][ni], 0, 0, 0);
  }

  auto wtile = [&](int s) {
    float* rw = &red[s][0];
#pragma unroll
    for (int mi = 0; mi < 4; ++mi)
#pragma unroll
      for (int ni = 0; ni < 2; ++ni)
#pragma unroll
        for (int r = 0; r < 4; ++r)
          rw[(mi * 16 + l4 * 4 + r) * RS + ni * 16 + l15] = acc[mi][ni][r];
  };
  auto atile = [&](int s) {
    const float* rr = &red[s][0];
#pragma unroll
    for (int mi = 0; mi < 4; ++mi)
#pragma unroll
      for (int ni = 0; ni < 2; ++ni)
#pragma unroll
        for (int r = 0; r < 4; ++r)
          acc[mi][ni][r] += rr[(mi * 16 + l4 * 4 + r) * RS + ni * 16 + l15];
  };

  if (wk >= 4) wtile((wk - 4) * 2 + wn);
  __syncthreads();
  if (wk < 4) atile(wk * 2 + wn);
  __syncthreads();
  if (wk == 2 || wk == 3) wtile((wk - 2) * 2 + wn);
  __syncthreads();
  if (wk < 2) atile(wk * 2 + wn);
  __syncthreads();
  if (wk == 1) wtile(wn);
  __syncthreads();
  if (wk == 0) { atile(wn); wtile(wn); }
  __syncthreads();

  {
    const int row = tid >> 4;
    const int c4  = tid & 15;
    float4 v = *reinterpret_cast<const float4*>(
        &red[c4 >> 3][row * RS + (c4 & 7) * 4]);
    *reinterpret_cast<float4*>(
        &out[(size_t)(m0 + row) * MOUT + n0 + c4 * 4]) = v;
  }
}

extern "C" void kernel_launch(void* const* d_in, const int* in_sizes, int n_in,
                              void* d_out, int out_size, void* d_ws, size_t ws_size,
                              hipStream_t stream) {
  const float* inp = (const float*)d_in[0];
  const float* sw  = (const float*)d_in[1];
  const float* qs  = (const float*)d_in[2];
  const int*   qi  = (const int*)d_in[3];
  float* out = (float*)d_out;
  unsigned short* xa = (unsigned short*)d_ws;                       // 2 MB
  unsigned short* qp = (unsigned short*)((char*)d_ws + (4 << 20));  // 4 MB
  auto pdst = [&](int v) {
    return (float*)((char*)d_ws + ((size_t)(16 + v) << 20));        // 1 MB each
  };

  prep_kernel<<<512, 256, 0, stream>>>(inp, sw, qs, xa);
  repack_kernel<<<128, 256, 0, stream>>>(qi, qp);

  constexpr int GRID = (BATCH / BM) * (MOUT / BN);   // 256

  // ---- ablation probes (scratch output; per-dispatch dur via rocprof) ----
  probe_kernel<0, 2><<<GRID, 1024, 0, stream>>>(xa, qp, pdst(0));   // full pipelined
  probe_kernel<1, 8><<<GRID, 1024, 0, stream>>>(xa, qp, pdst(1));   // q + LDS lookups
  probe_kernel<2, 8><<<GRID, 1024, 0, stream>>>(xa, qp, pdst(2));   // global loads only
  probe_kernel<3, 48><<<GRID, 1024, 0, stream>>>(xa, qp, pdst(3));  // MFMA only
  probe_kernel<4, 2><<<GRID, 1024, 0, stream>>>(xa, qp, pdst(4));   // full, no pipeline

  // ---- real output ----
  gemm_kernel<<<GRID, 1024, 0, stream>>>(xa, qp, out);
}

// Round 8
// 38.995 us; speedup vs baseline: 23.8668x; 23.8668x over previous
//
#include <hip/hip_runtime.h>

#define DI __device__ __forceinline__

constexpr int BATCH = 256;
constexpr int INF   = 4096;   // in_features
constexpr int NGRP  = 1024;   // INF/4
constexpr int MOUT  = 4096;   // out_features

constexpr int BN     = 64;    // n-cols per block (BM = 256 = full batch)
constexpr int KSPLIT = 4;
constexpr int KRANGE = INF / KSPLIT;   // 1024
constexpr int NST    = KRANGE / 64;    // 16 k-steps of BK=64

using bf16x8 = __attribute__((ext_vector_type(8))) short;
using f32x4  = __attribute__((ext_vector_type(4))) float;

// D4 half-codebook, stored as 2x the actual values (int8); actual = v * 0.5
__device__ __constant__ signed char D4_I8[512] = {
     0, 0, 0, 0,  -4, 0, 0, 0,  -2,-2,-2,-2,  -2,-2,-2, 0,  -2,-2,-2, 2,  -2,-2, 0,-2,  -2,-2, 0, 0,  -2,-2, 0, 2,
    -2,-2, 2,-2,  -2,-2, 2, 0,  -2,-2, 2, 2,  -2, 0,-2,-2,  -2, 0,-2, 0,  -2, 0,-2, 2,  -2, 0, 0,-2,  -2, 0, 0, 0,
    -2, 0, 0, 2,  -2, 0, 2,-2,  -2, 0, 2, 0,  -2, 0, 2, 2,  -2, 2,-2,-2,  -2, 2,-2, 0,  -2, 2,-2, 2,  -2, 2, 0,-2,
    -2, 2, 0, 0,  -2, 2, 0, 2,  -2, 2, 2,-2,  -2, 2, 2, 0,  -2, 2, 2, 2,   0,-4, 0, 0,   0,-2,-2,-2,   0,-2,-2, 0,
     0,-2,-2, 2,   0,-2, 0,-2,   0,-2, 0, 0,   0,-2, 0, 2,   0,-2, 2,-2,   0,-2, 2, 0,   0,-2, 2, 2,   0, 0,-4, 0,
     0, 0,-2,-2,   0, 0,-2, 0,   0, 0,-2, 2,   0, 0, 0,-4,   0, 0, 0,-2,
    -3,-1,-3,-1,  -3,-1,-3, 1,  -3,-1,-1,-3,  -3,-1,-1,-1,  -3,-1,-1, 1,  -3,-1,-1, 3,  -3,-1, 1,-3,  -3,-1, 1,-1,
    -3,-1, 1, 1,  -3,-1, 1, 3,  -3,-1, 3,-1,  -3,-1, 3, 1,  -3, 1,-3,-1,  -3, 1,-3, 1,  -3, 1,-1,-3,  -3, 1,-1,-1,
    -3, 1,-1, 1,  -3, 1,-1, 3,  -3, 1, 1,-3,  -3, 1, 1,-1,  -3, 1, 1, 1,  -3, 1, 1, 3,  -3, 1, 3,-1,  -3, 1, 3, 1,
    -3, 3,-1,-1,  -3, 3, 1,-1,  -3, 3, 1, 1,  -1,-3,-3,-1,  -1,-3,-3, 1,  -1,-3,-1,-3,  -1,-3,-1,-1,  -1,-3,-1, 1,
    -1,-3,-1, 3,  -1,-3, 1,-3,  -1,-3, 1,-1,  -1,-3, 1, 1,  -1,-3, 1, 3,  -1,-3, 3,-1,  -1,-3, 3, 1,  -1,-1,-3,-3,
    -1,-1,-3,-1,  -1,-1,-3, 1,  -1,-1,-3, 3,  -1,-1,-1,-3,  -1,-1,-1,-1,  -1,-1,-1, 1,  -1,-1,-1, 3,  -1,-1, 1,-3,
    -1,-1, 1,-1,  -1,-1, 1, 1,  -1,-1, 1, 3,  -1,-1, 3,-3,  -1,-1, 3,-1,  -1,-1, 3, 1,  -1,-1, 3, 3,  -1, 1,-3,-3,
    -1, 1,-3,-1,  -1, 1,-3, 1,  -1, 1,-3, 3,  -1, 1,-1,-3,  -1, 1,-1,-1,  -1, 1,-1, 1,  -1, 1,-1, 3,  -1, 1, 1,-3,
    -1, 1, 1,-1,  -1, 1, 1, 1,  -1, 1, 1, 3,  -1, 1, 3,-3,  -1, 1, 3,-1,  -1, 1, 3, 1,  -1, 1, 3, 3,  -1, 3,-3,-1,
    -1, 3,-3, 1,  -1, 3,-1,-3,  -1, 3,-1,-1,  -1, 3,-1, 1,  -1, 3,-1, 3,  -1, 3, 1,-3,  -1, 3, 1,-1,  -1, 3, 1, 1,
    -1, 3, 1, 3,  -1, 3, 3,-1,  -1, 3, 3, 1
};

DI unsigned short f2bf(float f) {  // f32 -> bf16 bits, round-to-nearest-even
  unsigned int u = __float_as_uint(f);
  u += 0x7fffu + ((u >> 16) & 1u);
  return (unsigned short)(u >> 16);
}

// Build Xa = scaled input in fragment-linear layout Xa[k>>5][m][(k>>3)&3][8]
__global__ __launch_bounds__(256) void prep_kernel(
    const float* __restrict__ inp, const float* __restrict__ sw,
    const float* __restrict__ qs, unsigned short* __restrict__ xa) {
  int i  = blockIdx.x * 256 + threadIdx.x;  // 16B slot id, 131072 total
  int j  = i & 3;                           // k-oct within 32-block
  int m  = (i >> 2) & 255;
  int kb = i >> 10;                         // k >> 5
  const float* ip = inp + (size_t)m * INF + kb * 32 + j * 8;
  float4 f0 = *reinterpret_cast<const float4*>(ip);
  float4 f1 = *reinterpret_cast<const float4*>(ip + 4);
  const float* sp = sw + kb * 32 + j * 8;
  float4 s0 = *reinterpret_cast<const float4*>(sp);
  float4 s1 = *reinterpret_cast<const float4*>(sp + 4);
  int g = kb * 8 + j * 2;
  float q0 = qs[g], q1 = qs[g + 1];
  union { unsigned short u[8]; uint4 v; } o;
  o.u[0] = f2bf(f0.x * s0.x * q0); o.u[1] = f2bf(f0.y * s0.y * q0);
  o.u[2] = f2bf(f0.z * s0.z * q0); o.u[3] = f2bf(f0.w * s0.w * q0);
  o.u[4] = f2bf(f1.x * s1.x * q1); o.u[5] = f2bf(f1.y * s1.y * q1);
  o.u[6] = f2bf(f1.z * s1.z * q1); o.u[7] = f2bf(f1.w * s1.w * q1);
  reinterpret_cast<uint4*>(xa)[i] = o.v;
}

// Repack Qidxs (int32 [MOUT][NGRP]) -> Qp u16 [B4=k>>5][n][j=(k>>3)&3] (4 MB).
__global__ __launch_bounds__(256) void repack_kernel(
    const int* __restrict__ qidx, unsigned short* __restrict__ qp) {
  __shared__ unsigned short lw[16384];     // 32 KB: [B4(128)][n(32)][j(4)]
  const int t  = threadIdx.x;
  const int n0 = blockIdx.x * 32;
  char* lwb = reinterpret_cast<char*>(lw);

  const int b4w   = t >> 1;
  const int cbase = b4w * 256 + ((2 * t) & 3) * 2;
  const int xk    = (b4w & 31) << 3;
  for (int r = 0; r < 32; ++r) {
    int4 v = *reinterpret_cast<const int4*>(
        qidx + (size_t)(n0 + r) * NGRP + t * 4);
    unsigned p01 = (v.x & 255) | ((v.y & 255) << 8) |
                   ((v.z & 255) << 16) | ((unsigned)(v.w & 255) << 24);
    *reinterpret_cast<unsigned*>(lwb + cbase + ((r * 8) ^ xk)) = p01;
  }
  __syncthreads();
  for (int it = 0; it < 16; ++it) {
    int b4 = it * 8 + (t >> 5);
    int n  = t & 31;
    unsigned long long v = *reinterpret_cast<const unsigned long long*>(
        lwb + b4 * 256 + ((n * 8) ^ ((b4 & 31) << 3)));
    *reinterpret_cast<unsigned long long*>(
        reinterpret_cast<char*>(qp) + (size_t)b4 * 32768 +
        (size_t)(n0 + n) * 8) = v;
  }
}

// Fused dequant-GEMM. Block = 512 thr / 8 waves, tile 256m x 64n, k-range
// 1024 (KSPLIT=4 across blocks, bid = ks*64+nt so ks-partners share an XCD).
// W dequantized ONCE into a double-buffered XOR-swizzled LDS tile (indices
// for all 16 steps preloaded into registers); A register-direct from
// fragment-linear Xa (1 step ahead); partials to scratch, no atomics.
__global__ __launch_bounds__(512, 2) void gemm_kernel(
    const unsigned short* __restrict__ xa, const unsigned short* __restrict__ qp,
    float* __restrict__ pt) {
  __shared__ unsigned long long tbl[256];    // sign-folded bf16x4 codebook
  __shared__ ulonglong2 wtv[2][512];         // 2 x 8 KB W-tile [n(64)][k(64)] bf16
  char* wtb = reinterpret_cast<char*>(&wtv[0][0]);

  const int tid  = threadIdx.x;              // 0..511
  const int lane = tid & 63;
  const int wave = tid >> 6;                 // 0..7
  const int wm   = wave >> 1;                // m quadrant (64 rows)
  const int wn   = wave & 1;                 // n half (32 cols)
  const int l15  = lane & 15, l4 = lane >> 4;

  const int bid = blockIdx.x;                // 0..255
  const int nt  = bid & 63;                  // xcd = nt % 8
  const int ks  = bid >> 6;                  // 0..3
  const int n0  = nt * BN;
  const int kb0 = ks * 32;                   // base B4 (k>>5)

  // ---- signed codebook table: tbl[i] = 4 packed bf16, tbl[i+128] = -tbl[i]
  if (tid < 256) {
    int r = tid & 127, sg = tid >> 7;
    unsigned long long v = 0;
#pragma unroll
    for (int j = 0; j < 4; ++j) {
      float f = (float)D4_I8[r * 4 + j] * 0.5f;
      unsigned int b = __float_as_uint(f) ^ (sg ? 0x80000000u : 0u);
      v |= (unsigned long long)(b >> 16) << (16 * j);
    }
    tbl[tid] = v;
  }

  // ---- preload ALL k-steps' packed indices (zero in-loop dequant latency)
  const int qn = tid >> 3, qoct = tid & 7;   // my (n-row, k-octet) slot
  unsigned short q16[NST];
#pragma unroll
  for (int ts = 0; ts < NST; ++ts)
    q16[ts] = *reinterpret_cast<const unsigned short*>(
        reinterpret_cast<const char*>(qp) +
        (size_t)(kb0 + ts * 2 + (qoct >> 2)) * 32768 +
        (size_t)(n0 + qn) * 8 + (qoct & 3) * 2);

  const unsigned wdst = (unsigned)(qn * 128 + qoct * 16) ^ ((unsigned)(qn & 7) << 4);
  auto dqw = [&](int buf, int ts) {          // dequant 8 weights -> 16B LDS write
    unsigned q = q16[ts];
    ulonglong2 v;
    v.x = tbl[q & 255];
    v.y = tbl[q >> 8];
    *reinterpret_cast<ulonglong2*>(wtb + buf * 8192 + wdst) = v;
  };

  // ---- A: register-direct fragment loads (1 KB contiguous per wave-frag)
  const unsigned short* ax = xa + ((size_t)(wm * 64 + l15) * 4 + l4) * 8;
  bf16x8 abuf[2][8];                         // [buf][kk*4+mi]
  auto aload = [&](int s, int t) {
    if (t < NST)
#pragma unroll
      for (int kk = 0; kk < 2; ++kk)
#pragma unroll
        for (int mi = 0; mi < 4; ++mi)
          abuf[s][kk * 4 + mi] = *reinterpret_cast<const bf16x8*>(
              ax + ((size_t)(kb0 + 2 * t + kk) * 1024 + mi * 64) * 8);
  };

  // ---- W fragment read (XOR-swizzled rows; nrow&7 == l15&7)
  const unsigned bswz = (unsigned)(l15 & 7) << 4;
  auto wread = [&](int buf, int kk, int ni) -> bf16x8 {
    unsigned off = ((unsigned)((wn * 32 + ni * 16 + l15) * 128 +
                               kk * 64 + l4 * 16)) ^ bswz;
    return *reinterpret_cast<const bf16x8*>(wtb + buf * 8192 + off);
  };

  f32x4 acc[4][2] = {};

  // ---- prologue
  aload(0, 0);
  __syncthreads();           // tbl ready
  dqw(0, 0);
  __syncthreads();           // W[0] ready

  // ---- k-loop: 16 steps of BK=64, one barrier per step
#pragma unroll
  for (int t = 0; t < NST; ++t) {
    if (t + 1 < NST) {
      aload((t + 1) & 1, t + 1);   // A for next step (global, overlapped)
      dqw((t + 1) & 1, t + 1);     // W for next step into other buffer
    }
#pragma unroll
    for (int kk = 0; kk < 2; ++kk) {
      bf16x8 b0 = wread(t & 1, kk, 0);
      bf16x8 b1 = wread(t & 1, kk, 1);
#pragma unroll
      for (int mi = 0; mi < 4; ++mi) {
        acc[mi][0] = __builtin_amdgcn_mfma_f32_16x16x32_bf16(
            abuf[t & 1][kk * 4 + mi], b0, acc[mi][0], 0, 0, 0);
        acc[mi][1] = __builtin_amdgcn_mfma_f32_16x16x32_bf16(
            abuf[t & 1][kk * 4 + mi], b1, acc[mi][1], 0, 0, 0);
      }
    }
    __syncthreads();
  }

  // ---- store partial tile (plain coalesced dword stores, no atomics)
  float* pw = pt + (size_t)ks * (BATCH * MOUT) +
              (size_t)(wm * 64 + l4 * 4) * MOUT + n0 + wn * 32 + l15;
#pragma unroll
  for (int mi = 0; mi < 4; ++mi)
#pragma unroll
    for (int ni = 0; ni < 2; ++ni)
#pragma unroll
      for (int r = 0; r < 4; ++r)
        pw[(size_t)(mi * 16 + r) * MOUT + ni * 16] = acc[mi][ni][r];
}

// Sum the KSPLIT partial planes -> out. bid = mseg*64 + nt (xcd matches gemm).
__global__ __launch_bounds__(256) void reduce_kernel(
    const float* __restrict__ pt, float* __restrict__ out) {
  const int bid  = blockIdx.x;
  const int nt   = bid & 63, mseg = bid >> 6;
  const int t    = threadIdx.x;
  const int m    = mseg * 16 + (t >> 4);
  const int n    = nt * BN + (t & 15) * 4;
  const size_t off = (size_t)m * MOUT + n;
  float4 s = make_float4(0.f, 0.f, 0.f, 0.f);
#pragma unroll
  for (int k = 0; k < KSPLIT; ++k) {
    float4 p = *reinterpret_cast<const float4*>(
        pt + (size_t)k * (BATCH * MOUT) + off);
    s.x += p.x; s.y += p.y; s.z += p.z; s.w += p.w;
  }
  *reinterpret_cast<float4*>(out + off) = s;
}

extern "C" void kernel_launch(void* const* d_in, const int* in_sizes, int n_in,
                              void* d_out, int out_size, void* d_ws, size_t ws_size,
                              hipStream_t stream) {
  const float* inp = (const float*)d_in[0];
  const float* sw  = (const float*)d_in[1];
  const float* qs  = (const float*)d_in[2];
  const int*   qi  = (const int*)d_in[3];
  float* out = (float*)d_out;
  unsigned short* xa = (unsigned short*)d_ws;                       // 2 MB
  unsigned short* qp = (unsigned short*)((char*)d_ws + (4 << 20));  // 4 MB
  float* pt = (float*)((char*)d_ws + (8 << 20));                    // 16 MB

  prep_kernel<<<512, 256, 0, stream>>>(inp, sw, qs, xa);
  repack_kernel<<<128, 256, 0, stream>>>(qi, qp);

  constexpr int GRID = (MOUT / BN) * KSPLIT;   // 64 * 4 = 256
  gemm_kernel<<<GRID, 512, 0, stream>>>(xa, qp, pt);

  reduce_kernel<<<1024, 256, 0, stream>>>(pt, out);
}

// Round 9
// 37.087 us; speedup vs baseline: 25.0950x; 1.0515x over previous
//
#include <hip/hip_runtime.h>

#define DI __device__ __forceinline__

constexpr int BATCH = 256;
constexpr int INF   = 4096;   // in_features
constexpr int NGRP  = 1024;   // INF/4
constexpr int MOUT  = 4096;   // out_features

constexpr int BN     = 64;    // n-cols per block (BM = 256 = full batch)
constexpr int KSPLIT = 4;     // k-split across blocks; x2 halves in-block -> 8 planes

using bf16x8 = __attribute__((ext_vector_type(8))) short;
using f32x4  = __attribute__((ext_vector_type(4))) float;

// D4 half-codebook, stored as 2x the actual values (int8); actual = v * 0.5
__device__ __constant__ signed char D4_I8[512] = {
     0, 0, 0, 0,  -4, 0, 0, 0,  -2,-2,-2,-2,  -2,-2,-2, 0,  -2,-2,-2, 2,  -2,-2, 0,-2,  -2,-2, 0, 0,  -2,-2, 0, 2,
    -2,-2, 2,-2,  -2,-2, 2, 0,  -2,-2, 2, 2,  -2, 0,-2,-2,  -2, 0,-2, 0,  -2, 0,-2, 2,  -2, 0, 0,-2,  -2, 0, 0, 0,
    -2, 0, 0, 2,  -2, 0, 2,-2,  -2, 0, 2, 0,  -2, 0, 2, 2,  -2, 2,-2,-2,  -2, 2,-2, 0,  -2, 2,-2, 2,  -2, 2, 0,-2,
    -2, 2, 0, 0,  -2, 2, 0, 2,  -2, 2, 2,-2,  -2, 2, 2, 0,  -2, 2, 2, 2,   0,-4, 0, 0,   0,-2,-2,-2,   0,-2,-2, 0,
     0,-2,-2, 2,   0,-2, 0,-2,   0,-2, 0, 0,   0,-2, 0, 2,   0,-2, 2,-2,   0,-2, 2, 0,   0,-2, 2, 2,   0, 0,-4, 0,
     0, 0,-2,-2,   0, 0,-2, 0,   0, 0,-2, 2,   0, 0, 0,-4,   0, 0, 0,-2,
    -3,-1,-3,-1,  -3,-1,-3, 1,  -3,-1,-1,-3,  -3,-1,-1,-1,  -3,-1,-1, 1,  -3,-1,-1, 3,  -3,-1, 1,-3,  -3,-1, 1,-1,
    -3,-1, 1, 1,  -3,-1, 1, 3,  -3,-1, 3,-1,  -3,-1, 3, 1,  -3, 1,-3,-1,  -3, 1,-3, 1,  -3, 1,-1,-3,  -3, 1,-1,-1,
    -3, 1,-1, 1,  -3, 1,-1, 3,  -3, 1, 1,-3,  -3, 1, 1,-1,  -3, 1, 1, 1,  -3, 1, 1, 3,  -3, 1, 3,-1,  -3, 1, 3, 1,
    -3, 3,-1,-1,  -3, 3, 1,-1,  -3, 3, 1, 1,  -1,-3,-3,-1,  -1,-3,-3, 1,  -1,-3,-1,-3,  -1,-3,-1,-1,  -1,-3,-1, 1,
    -1,-3,-1, 3,  -1,-3, 1,-3,  -1,-3, 1,-1,  -1,-3, 1, 1,  -1,-3, 1, 3,  -1,-3, 3,-1,  -1,-3, 3, 1,  -1,-1,-3,-3,
    -1,-1,-3,-1,  -1,-1,-3, 1,  -1,-1,-3, 3,  -1,-1,-1,-3,  -1,-1,-1,-1,  -1,-1,-1, 1,  -1,-1,-1, 3,  -1,-1, 1,-3,
    -1,-1, 1,-1,  -1,-1, 1, 1,  -1,-1, 1, 3,  -1,-1, 3,-3,  -1,-1, 3,-1,  -1,-1, 3, 1,  -1,-1, 3, 3,  -1, 1,-3,-3,
    -1, 1,-3,-1,  -1, 1,-3, 1,  -1, 1,-3, 3,  -1, 1,-1,-3,  -1, 1,-1,-1,  -1, 1,-1, 1,  -1, 1,-1, 3,  -1, 1, 1,-3,
    -1, 1, 1,-1,  -1, 1, 1, 1,  -1, 1, 1, 3,  -1, 1, 3,-3,  -1, 1, 3,-1,  -1, 1, 3, 1,  -1, 1, 3, 3,  -1, 3,-3,-1,
    -1, 3,-3, 1,  -1, 3,-1,-3,  -1, 3,-1,-1,  -1, 3,-1, 1,  -1, 3,-1, 3,  -1, 3, 1,-3,  -1, 3, 1,-1,  -1, 3, 1, 1,
    -1, 3, 1, 3,  -1, 3, 3,-1,  -1, 3, 3, 1
};

DI unsigned short f2bf(float f) {  // f32 -> bf16 bits, round-to-nearest-even
  unsigned int u = __float_as_uint(f);
  u += 0x7fffu + ((u >> 16) & 1u);
  return (unsigned short)(u >> 16);
}

// Build Xa = scaled input in fragment-linear layout Xa[k>>5][m][(k>>3)&3][8]
__global__ __launch_bounds__(256) void prep_kernel(
    const float* __restrict__ inp, const float* __restrict__ sw,
    const float* __restrict__ qs, unsigned short* __restrict__ xa) {
  int i  = blockIdx.x * 256 + threadIdx.x;  // 16B slot id, 131072 total
  int j  = i & 3;                           // k-oct within 32-block
  int m  = (i >> 2) & 255;
  int kb = i >> 10;                         // k >> 5
  const float* ip = inp + (size_t)m * INF + kb * 32 + j * 8;
  float4 f0 = *reinterpret_cast<const float4*>(ip);
  float4 f1 = *reinterpret_cast<const float4*>(ip + 4);
  const float* sp = sw + kb * 32 + j * 8;
  float4 s0 = *reinterpret_cast<const float4*>(sp);
  float4 s1 = *reinterpret_cast<const float4*>(sp + 4);
  int g = kb * 8 + j * 2;
  float q0 = qs[g], q1 = qs[g + 1];
  union { unsigned short u[8]; uint4 v; } o;
  o.u[0] = f2bf(f0.x * s0.x * q0); o.u[1] = f2bf(f0.y * s0.y * q0);
  o.u[2] = f2bf(f0.z * s0.z * q0); o.u[3] = f2bf(f0.w * s0.w * q0);
  o.u[4] = f2bf(f1.x * s1.x * q1); o.u[5] = f2bf(f1.y * s1.y * q1);
  o.u[6] = f2bf(f1.z * s1.z * q1); o.u[7] = f2bf(f1.w * s1.w * q1);
  reinterpret_cast<uint4*>(xa)[i] = o.v;
}

// Repack Qidxs (int32 [MOUT][NGRP]) -> Qp u16 [B4=k>>5][n][j=(k>>3)&3] (4 MB).
__global__ __launch_bounds__(256) void repack_kernel(
    const int* __restrict__ qidx, unsigned short* __restrict__ qp) {
  __shared__ unsigned short lw[16384];     // 32 KB: [B4(128)][n(32)][j(4)]
  const int t  = threadIdx.x;
  const int n0 = blockIdx.x * 32;
  char* lwb = reinterpret_cast<char*>(lw);

  const int b4w   = t >> 1;
  const int cbase = b4w * 256 + ((2 * t) & 3) * 2;
  const int xk    = (b4w & 31) << 3;
  for (int r = 0; r < 32; ++r) {
    int4 v = *reinterpret_cast<const int4*>(
        qidx + (size_t)(n0 + r) * NGRP + t * 4);
    unsigned p01 = (v.x & 255) | ((v.y & 255) << 8) |
                   ((v.z & 255) << 16) | ((unsigned)(v.w & 255) << 24);
    *reinterpret_cast<unsigned*>(lwb + cbase + ((r * 8) ^ xk)) = p01;
  }
  __syncthreads();
  for (int it = 0; it < 16; ++it) {
    int b4 = it * 8 + (t >> 5);
    int n  = t & 31;
    unsigned long long v = *reinterpret_cast<const unsigned long long*>(
        lwb + b4 * 256 + ((n * 8) ^ ((b4 & 31) << 3)));
    *reinterpret_cast<unsigned long long*>(
        reinterpret_cast<char*>(qp) + (size_t)b4 * 32768 +
        (size_t)(n0 + n) * 8) = v;
  }
}

// ---------------- fully-unrolled named-register fused dequant-GEMM ---------
// Block = 512 thr / 8 waves = 4 m-quadrants x 2 k-halves. Tile 256m x 64n,
// k-range 1024 (KSPLIT=4). W staged in 4-tile (32KB) granules, double
// buffered -> 5 barriers total. All q preloaded (16 named regs); A frags
// double-banked (16 named bf16x8); acc = 16 named f32x4. No arrays, no
// lambdas -> no scratch possible. Each half writes its own partial plane.

#define MM(A, B, C) C = __builtin_amdgcn_mfma_f32_16x16x32_bf16(A, B, C, 0, 0, 0)
#define LD8(p) (*reinterpret_cast<const bf16x8*>(p))

#define DQW(TB, Q) do { unsigned __q = (Q); ulonglong2 __v; \
    __v.x = tbl[__q & 255]; __v.y = tbl[__q >> 8]; \
    *reinterpret_cast<ulonglong2*>(wsm + (TB) + wslot) = __v; } while (0)

#define AL(B, SI) do { \
    B##_0 = LD8(axb + (SI)*32768 +     0); \
    B##_1 = LD8(axb + (SI)*32768 +  1024); \
    B##_2 = LD8(axb + (SI)*32768 +  2048); \
    B##_3 = LD8(axb + (SI)*32768 +  3072); \
    B##_4 = LD8(axb + (SI)*32768 + 16384); \
    B##_5 = LD8(axb + (SI)*32768 + 17408); \
    B##_6 = LD8(axb + (SI)*32768 + 18432); \
    B##_7 = LD8(axb + (SI)*32768 + 19456); } while (0)

#define BODY(TC, AB, STG, TS0, QA, TS1, QB, ARL, SI) do { \
    if (STG) { DQW(TS0, QA); DQW(TS1, QB); } \
    bf16x8 b0 = LD8(wcb + (TC) +    0 + wrA); \
    bf16x8 b1 = LD8(wcb + (TC) + 2048 + wrA); \
    bf16x8 b2 = LD8(wcb + (TC) + 4096 + wrA); \
    bf16x8 b3 = LD8(wcb + (TC) + 6144 + wrA); \
    MM(AB##_0, b0, c00); MM(AB##_0, b1, c01); MM(AB##_0, b2, c02); MM(AB##_0, b3, c03); \
    MM(AB##_1, b0, c10); MM(AB##_1, b1, c11); MM(AB##_1, b2, c12); MM(AB##_1, b3, c13); \
    MM(AB##_2, b0, c20); MM(AB##_2, b1, c21); MM(AB##_2, b2, c22); MM(AB##_2, b3, c23); \
    MM(AB##_3, b0, c30); MM(AB##_3, b1, c31); MM(AB##_3, b2, c32); MM(AB##_3, b3, c33); \
    b0 = LD8(wcb + (TC) +    0 + wrB); \
    b1 = LD8(wcb + (TC) + 2048 + wrB); \
    b2 = LD8(wcb + (TC) + 4096 + wrB); \
    b3 = LD8(wcb + (TC) + 6144 + wrB); \
    MM(AB##_4, b0, c00); MM(AB##_4, b1, c01); MM(AB##_4, b2, c02); MM(AB##_4, b3, c03); \
    MM(AB##_5, b0, c10); MM(AB##_5, b1, c11); MM(AB##_5, b2, c12); MM(AB##_5, b3, c13); \
    MM(AB##_6, b0, c20); MM(AB##_6, b1, c21); MM(AB##_6, b2, c22); MM(AB##_6, b3, c23); \
    MM(AB##_7, b0, c30); MM(AB##_7, b1, c31); MM(AB##_7, b2, c32); MM(AB##_7, b3, c33); \
    if (ARL) AL(AB, SI); } while (0)

__global__ __launch_bounds__(512, 2) void gemm_kernel(
    const unsigned short* __restrict__ xa, const unsigned short* __restrict__ qp,
    float* __restrict__ pt) {
  __shared__ unsigned long long tbl[256];    // sign-folded bf16x4 codebook
  __shared__ ulonglong2 wsv[4096];           // 64 KB: 2 bufs x 4 tiles x 8 KB
  char* wsm = reinterpret_cast<char*>(wsv);

  const int tid  = threadIdx.x;              // 0..511
  const int lane = tid & 63;
  const int wave = tid >> 6;                 // 0..7
  const int wm   = wave & 3;                 // m quadrant (64 rows)
  const int h    = wave >> 2;                // k half (512 k)
  const int l15  = lane & 15, l4 = lane >> 4;

  const int bid = blockIdx.x;                // 0..255
  const int nt  = bid & 63, ks = bid >> 6;
  const int n0  = nt * BN;

  // staging slot: thread -> (n-row qn, k-octet oct) of each 64x64 tile
  const int qn  = tid >> 3, oct = tid & 7;
  const unsigned wslot =
      ((unsigned)(qn * 128 + oct * 16)) ^ ((unsigned)(qn & 7) << 4);

  // ---- preload ALL 16 packed q-indices (named regs, issued first)
  const char* qpb = reinterpret_cast<const char*>(qp) +
      (size_t)(ks * 32 + (oct >> 2)) * 32768 + (size_t)(n0 + qn) * 8 +
      (oct & 3) * 2;
#define QLD(K) ((unsigned)*reinterpret_cast<const unsigned short*>(qpb + (K) * 65536))
  const unsigned Q00 = QLD(0),  Q01 = QLD(1),  Q02 = QLD(2),  Q03 = QLD(3);
  const unsigned Q04 = QLD(4),  Q05 = QLD(5),  Q06 = QLD(6),  Q07 = QLD(7);
  const unsigned Q10 = QLD(8),  Q11 = QLD(9),  Q12 = QLD(10), Q13 = QLD(11);
  const unsigned Q14 = QLD(12), Q15 = QLD(13), Q16 = QLD(14), Q17 = QLD(15);
#undef QLD

  // ---- signed codebook table: tbl[i] = 4 packed bf16, tbl[i+128] = -tbl[i]
  if (tid < 256) {
    int r = tid & 127, sg = tid >> 7;
    unsigned long long v = 0;
#pragma unroll
    for (int j = 0; j < 4; ++j) {
      float f = (float)D4_I8[r * 4 + j] * 0.5f;
      unsigned int b = __float_as_uint(f) ^ (sg ? 0x80000000u : 0u);
      v |= (unsigned long long)(b >> 16) << (16 * j);
    }
    tbl[tid] = v;
  }

  // ---- per-wave bases
  const char* axb = reinterpret_cast<const char*>(xa) +
      (size_t)(ks * 32 + h * 16) * 16384 + (size_t)(wm * 64 + l15) * 64 +
      l4 * 16;
  const char* wcb = wsm + h * 16384;         // my half's tile pair base
  const unsigned xsw = (unsigned)(l15 & 7) << 4;
  const unsigned wrA = ((unsigned)(l15 * 128 +  0 + l4 * 16)) ^ xsw;  // kk=0
  const unsigned wrB = ((unsigned)(l15 * 128 + 64 + l4 * 16)) ^ xsw;  // kk=1

  f32x4 c00 = {}, c01 = {}, c02 = {}, c03 = {};
  f32x4 c10 = {}, c11 = {}, c12 = {}, c13 = {};
  f32x4 c20 = {}, c21 = {}, c22 = {}, c23 = {};
  f32x4 c30 = {}, c31 = {}, c32 = {}, c33 = {};
  bf16x8 P0_0, P0_1, P0_2, P0_3, P0_4, P0_5, P0_6, P0_7;
  bf16x8 P1_0, P1_1, P1_2, P1_3, P1_4, P1_5, P1_6, P1_7;

  // ---- prologue: A banks (steps 0,1) + first 4 W tiles into buf0
  AL(P0, 0);
  AL(P1, 1);
  __syncthreads();                           // tbl ready
  DQW(0,     Q00); DQW(8192,  Q01);
  DQW(16384, Q10); DQW(24576, Q11);
  __syncthreads();                           // buf0 ready

  // ---- 4 supersteps x 2 bodies, fully unrolled, 1 barrier each
  BODY(0,            P0, 1, 32768 + 0,     Q02, 32768 + 8192,  Q03, 1, 2);
  BODY(8192,         P1, 1, 32768 + 16384, Q12, 32768 + 24576, Q13, 1, 3);
  __syncthreads();
  BODY(32768 + 0,    P0, 1, 0,             Q04, 8192,          Q05, 1, 4);
  BODY(32768 + 8192, P1, 1, 16384,         Q14, 24576,         Q15, 1, 5);
  __syncthreads();
  BODY(0,            P0, 1, 32768 + 0,     Q06, 32768 + 8192,  Q07, 1, 6);
  BODY(8192,         P1, 1, 32768 + 16384, Q16, 32768 + 24576, Q17, 1, 7);
  __syncthreads();
  BODY(32768 + 0,    P0, 0, 0, Q00, 0, Q00, 0, 0);
  BODY(32768 + 8192, P1, 0, 0, Q00, 0, Q00, 0, 0);

  // ---- store partial plane (ks*2 + h), plain coalesced dword stores
  float* pw = pt + (size_t)(ks * 2 + h) * (BATCH * MOUT) +
              (size_t)(wm * 64 + l4 * 4) * MOUT + (n0 + l15);
#define ST4(C, MI, NI) do { \
    pw[(size_t)((MI)*16 + 0) * MOUT + (NI)*16] = C[0]; \
    pw[(size_t)((MI)*16 + 1) * MOUT + (NI)*16] = C[1]; \
    pw[(size_t)((MI)*16 + 2) * MOUT + (NI)*16] = C[2]; \
    pw[(size_t)((MI)*16 + 3) * MOUT + (NI)*16] = C[3]; } while (0)
  ST4(c00, 0, 0); ST4(c01, 0, 1); ST4(c02, 0, 2); ST4(c03, 0, 3);
  ST4(c10, 1, 0); ST4(c11, 1, 1); ST4(c12, 1, 2); ST4(c13, 1, 3);
  ST4(c20, 2, 0); ST4(c21, 2, 1); ST4(c22, 2, 2); ST4(c23, 2, 3);
  ST4(c30, 3, 0); ST4(c31, 3, 1); ST4(c32, 3, 2); ST4(c33, 3, 3);
#undef ST4
}

// Sum the 8 partial planes -> out.
__global__ __launch_bounds__(256) void reduce_kernel(
    const float* __restrict__ pt, float* __restrict__ out) {
  const int bid  = blockIdx.x;
  const int nt   = bid & 63, mseg = bid >> 6;
  const int t    = threadIdx.x;
  const int m    = mseg * 16 + (t >> 4);
  const int n    = nt * BN + (t & 15) * 4;
  const size_t off = (size_t)m * MOUT + n;
  float4 s = make_float4(0.f, 0.f, 0.f, 0.f);
#pragma unroll
  for (int k = 0; k < 8; ++k) {
    float4 p = *reinterpret_cast<const float4*>(
        pt + (size_t)k * (BATCH * MOUT) + off);
    s.x += p.x; s.y += p.y; s.z += p.z; s.w += p.w;
  }
  *reinterpret_cast<float4*>(out + off) = s;
}

extern "C" void kernel_launch(void* const* d_in, const int* in_sizes, int n_in,
                              void* d_out, int out_size, void* d_ws, size_t ws_size,
                              hipStream_t stream) {
  const float* inp = (const float*)d_in[0];
  const float* sw  = (const float*)d_in[1];
  const float* qs  = (const float*)d_in[2];
  const int*   qi  = (const int*)d_in[3];
  float* out = (float*)d_out;
  unsigned short* xa = (unsigned short*)d_ws;                       // 2 MB
  unsigned short* qp = (unsigned short*)((char*)d_ws + (4 << 20));  // 4 MB
  float* pt = (float*)((char*)d_ws + (8 << 20));                    // 32 MB

  prep_kernel<<<512, 256, 0, stream>>>(inp, sw, qs, xa);
  repack_kernel<<<128, 256, 0, stream>>>(qi, qp);

  constexpr int GRID = (MOUT / BN) * KSPLIT;   // 64 * 4 = 256
  gemm_kernel<<<GRID, 512, 0, stream>>>(xa, qp, pt);

  reduce_kernel<<<1024, 256, 0, stream>>>(pt, out);
}